// Round 8
// baseline (303.483 us; speedup 1.0000x reference)
//
#include <hip/hip_runtime.h>
#include <hip/hip_bf16.h>

typedef __attribute__((ext_vector_type(8))) short bf16x8;
typedef __attribute__((ext_vector_type(4))) float f32x4;
typedef __attribute__((ext_vector_type(4), aligned(4))) float f32x4u;
typedef __attribute__((ext_vector_type(2), aligned(4))) float f32x2u;

__device__ __forceinline__ unsigned short f2bf(float f) {
    unsigned int u = __float_as_uint(f);
    unsigned int r = (u + 0x7fffu + ((u >> 16) & 1u)) >> 16;
    return (unsigned short)r;
}
__device__ __forceinline__ float bflo(unsigned int u) { return __uint_as_float(u << 16); }
__device__ __forceinline__ float bfhi(unsigned int u) { return __uint_as_float(u & 0xffff0000u); }

// ---- merged prep: blocks 0..63 -> bt2; block 64 -> consts; blocks 65.. -> out=x ----
// bt2[c][k]: W2^T bf16, c in [0,256), k in [0,64). k==63 row = 0 (t folded into c0).
// bt_M[col][p] = (ew2 @ cw1[128:160])^T bf16 [128][32];
// c0[j] = cb1[j] + eb2@cw1[128:160] + t*(cw1[63]+cw1[127])
__global__ void prep_merged_kernel(
    const float* __restrict__ x, float* __restrict__ out, int n_out,
    const float* __restrict__ cw1, unsigned short* __restrict__ bt2,
    const float* __restrict__ ew2, const float* __restrict__ eb2,
    const float* __restrict__ cb1, const int* __restrict__ tptr,
    unsigned short* __restrict__ bt_M, float* __restrict__ c0)
{
    const int b = blockIdx.x, tid = threadIdx.x;
    if (b < 64) {
        int idx = b * 256 + tid;
        int n = idx >> 6, k = idx & 63;
        float v = 0.f;
        if (k < 63) v = (n < 128) ? cw1[k * 128 + n] : cw1[(64 + k) * 128 + (n - 128)];
        bt2[n * 64 + k] = f2bf(v);
    } else if (b == 64) {
        if (tid < 128) {
            int j = tid;
            float t = (float)tptr[0];
            float cacc = cb1[j] + t * (cw1[63 * 128 + j] + cw1[127 * 128 + j]);
            float m[32];
            #pragma unroll
            for (int p = 0; p < 32; ++p) m[p] = 0.f;
            for (int i = 0; i < 32; ++i) {
                float w = cw1[(128 + i) * 128 + j];
                cacc = fmaf(eb2[i], w, cacc);
                #pragma unroll
                for (int p = 0; p < 32; ++p) m[p] = fmaf(ew2[p * 32 + i], w, m[p]);
            }
            c0[j] = cacc;
            #pragma unroll
            for (int p = 0; p < 32; ++p) bt_M[j * 32 + p] = f2bf(m[p]);
        }
    } else {
        int i = (b - 65) * 256 + tid;
        if (i < n_out) out[i] = x[i];
    }
}

__device__ __forceinline__ bf16x8 load8_bf(const float* p) {
    f32x4u a = *(const f32x4u*)p;
    f32x4u b = *(const f32x4u*)(p + 4);
    bf16x8 r;
    r[0] = f2bf(a[0]); r[1] = f2bf(a[1]); r[2] = f2bf(a[2]); r[3] = f2bf(a[3]);
    r[4] = f2bf(b[0]); r[5] = f2bf(b[1]); r[6] = f2bf(b[2]); r[7] = f2bf(b[3]);
    return r;
}
__device__ __forceinline__ bf16x8 load7z_bf(const float* p) {
    f32x4u a = *(const f32x4u*)p;
    f32x2u b = *(const f32x2u*)(p + 4);
    float c = p[6];
    bf16x8 r;
    r[0] = f2bf(a[0]); r[1] = f2bf(a[1]); r[2] = f2bf(a[2]); r[3] = f2bf(a[3]);
    r[4] = f2bf(b[0]); r[5] = f2bf(b[1]); r[6] = f2bf(c);  r[7] = 0;
    return r;
}

// UV layout (PERMUTED for 64B-contiguous per-(node,half,kq) reads):
// short index within node = half*128 + kq*32 + g*4 + r, where original
// col c = (half*8+g)*16 + kq*4 + r.  U (half=0) = cond@Wtop, V (half=1) = cond@Wmid.
__global__ __launch_bounds__(256) void prep_uv_kernel(
    const float* __restrict__ cond, const unsigned short* __restrict__ bt2,
    unsigned short* __restrict__ UV, int BN)
{
    const int tid = threadIdx.x, lane = tid & 63, wid = tid >> 6;
    const int fr = lane & 15, kq = lane >> 4;
    int node = blockIdx.x * 64 + wid * 16 + fr;
    if (node >= BN) node = BN - 1;

    const float* cp = cond + (long)node * 63;
    bf16x8 b0 = load8_bf(cp + 8 * kq);
    bf16x8 b1 = (kq < 3) ? load8_bf(cp + 32 + 8 * kq) : load7z_bf(cp + 56);

    char* UVb = (char*)UV;
    const unsigned nb = (unsigned)node * 512u + (unsigned)(kq * 64);

    #pragma unroll
    for (int n = 0; n < 16; ++n) {
        // lane holds cols c = n*16 + kq*4 + r (r=0..3) for this node
        bf16x8 a0 = *reinterpret_cast<const bf16x8*>(&bt2[(n * 16 + fr) * 64 + 8 * kq]);
        bf16x8 a1 = *reinterpret_cast<const bf16x8*>(&bt2[(n * 16 + fr) * 64 + 32 + 8 * kq]);
        f32x4 acc = (f32x4){0.f, 0.f, 0.f, 0.f};
        acc = __builtin_amdgcn_mfma_f32_16x16x32_bf16(a0, b0, acc, 0, 0, 0);
        acc = __builtin_amdgcn_mfma_f32_16x16x32_bf16(a1, b1, acc, 0, 0, 0);
        uint2 pk;
        pk.x = (unsigned)f2bf(acc[0]) | ((unsigned)f2bf(acc[1]) << 16);
        pk.y = (unsigned)f2bf(acc[2]) | ((unsigned)f2bf(acc[3]) << 16);
        unsigned off = nb + ((n & 8) ? 256u : 0u) + (unsigned)((n & 7) * 8);
        *reinterpret_cast<uint2*>(UVb + off) = pk;
    }
}

__global__ __launch_bounds__(256, 3) void edge_kernel(
    const float* __restrict__ x, const float* __restrict__ edge_dist,
    const float* __restrict__ ew1, const float* __restrict__ eb1,
    const unsigned short* __restrict__ bt_M, const float* __restrict__ c0f,
    const float* __restrict__ cw2, const unsigned short* __restrict__ UV,
    const int* __restrict__ edge_index, float* __restrict__ out, int E)
{
    __shared__ __align__(16) unsigned short s_lds[128][40];
    __shared__ int srcl[128];
    __shared__ int dstl[128];
    __shared__ float cw_lds[128];

    const int tid = threadIdx.x, lane = tid & 63, wid = tid >> 6;
    const int fr = lane & 15, kq = lane >> 4;
    const int e0 = blockIdx.x * 128;

    // phase A: waves 0-1 silu (wave-uniform ew1 -> s_load); waves 2-3 indices
    if (tid < 128) {
        int e = e0 + tid; if (e >= E) e = E - 1;
        float dist = edge_dist[e];
        #pragma unroll
        for (int i = 0; i < 16; ++i) {
            float v0 = fmaf(dist, ew1[2 * i],     eb1[2 * i]);
            float v1 = fmaf(dist, ew1[2 * i + 1], eb1[2 * i + 1]);
            float s0 = v0 / (1.f + __expf(-v0));
            float s1 = v1 / (1.f + __expf(-v1));
            unsigned pk = (unsigned)f2bf(s0) | ((unsigned)f2bf(s1) << 16);
            *reinterpret_cast<unsigned*>(&s_lds[tid][2 * i]) = pk;
        }
    } else {
        int r = tid - 128;
        int e = e0 + r; if (e >= E) e = E - 1;
        srcl[r] = edge_index[e];
        dstl[r] = edge_index[E + e];
    }
    __syncthreads();

    // B-frags: lane(col=fr,kq) holds s[edge][k=8kq+j]
    bf16x8 sb[2];
    #pragma unroll
    for (int m = 0; m < 2; ++m)
        sb[m] = *reinterpret_cast<const bf16x8*>(&s_lds[wid * 32 + m * 16 + fr][8 * kq]);

    // UV bases: 64B contiguous per (edge, half) at this lane's kq
    unsigned bu[2], bv[2];
    #pragma unroll
    for (int m = 0; m < 2; ++m) {
        int row = wid * 32 + m * 16 + fr;
        bu[m] = (unsigned)srcl[row] * 512u + (unsigned)(kq * 64);
        bv[m] = (unsigned)dstl[row] * 512u + 256u + (unsigned)(kq * 64);
    }

    // ---- issue ALL 16 UV loads up front (one latency, hidden under MFMA+silu) ----
    const char* UVb = (const char*)UV;
    uint4 Lu[2][4], Lv[2][4];
    #pragma unroll
    for (int m = 0; m < 2; ++m)
        #pragma unroll
        for (int i = 0; i < 4; ++i) {
            Lu[m][i] = *reinterpret_cast<const uint4*>(UVb + bu[m] + i * 16);
            Lv[m][i] = *reinterpret_cast<const uint4*>(UVb + bv[m] + i * 16);
        }

    float psum[2] = {0.f, 0.f};
    #pragma unroll
    for (int nh = 0; nh < 2; ++nh) {
        f32x4 acc[2][4];
        #pragma unroll
        for (int n = 0; n < 4; ++n) {
            f32x4u c = *reinterpret_cast<const f32x4u*>(c0f + (nh * 4 + n) * 16 + kq * 4);
            acc[0][n] = (f32x4){c[0], c[1], c[2], c[3]};
            acc[1][n] = acc[0][n];
        }
        #pragma unroll
        for (int n = 0; n < 4; ++n) {
            bf16x8 aw = *reinterpret_cast<const bf16x8*>(&bt_M[((nh * 4 + n) * 16 + fr) * 32 + 8 * kq]);
            acc[0][n] = __builtin_amdgcn_mfma_f32_16x16x32_bf16(aw, sb[0], acc[0][n], 0, 0, 0);
            acc[1][n] = __builtin_amdgcn_mfma_f32_16x16x32_bf16(aw, sb[1], acc[1][n], 0, 0, 0);
        }
        #pragma unroll
        for (int n = 0; n < 4; ++n) {
            const int g = nh * 4 + n;             // compile-time
            f32x4u w2 = *reinterpret_cast<const f32x4u*>(cw2 + g * 16 + kq * 4);
            #pragma unroll
            for (int m = 0; m < 2; ++m) {
                unsigned du0 = (g & 1) ? Lu[m][g >> 1].z : Lu[m][g >> 1].x;
                unsigned du1 = (g & 1) ? Lu[m][g >> 1].w : Lu[m][g >> 1].y;
                unsigned dv0 = (g & 1) ? Lv[m][g >> 1].z : Lv[m][g >> 1].x;
                unsigned dv1 = (g & 1) ? Lv[m][g >> 1].w : Lv[m][g >> 1].y;
                float uf[4] = {bflo(du0), bfhi(du0), bflo(du1), bfhi(du1)};
                float vf[4] = {bflo(dv0), bfhi(dv0), bflo(dv1), bfhi(dv1)};
                #pragma unroll
                for (int r = 0; r < 4; ++r) {
                    float h = acc[m][n][r] + uf[r] + vf[r];
                    float sil = h / (1.f + __expf(-h));
                    psum[m] = fmaf(sil, w2[r], psum[m]);
                }
            }
        }
    }

    // reduce across the 4 kq groups
    #pragma unroll
    for (int m = 0; m < 2; ++m) {
        psum[m] += __shfl_xor(psum[m], 16, 64);
        psum[m] += __shfl_xor(psum[m], 32, 64);
    }
    if (kq == 0) {
        #pragma unroll
        for (int m = 0; m < 2; ++m)
            cw_lds[wid * 32 + m * 16 + fr] = psum[m];
    }
    __syncthreads();

    if (tid < 128) {
        int e = e0 + tid;
        if (e < E) {
            float coord_w = cw_lds[tid];
            int src = srcl[tid];
            int dst = dstl[tid];
            float dx = x[src * 3 + 0] - x[dst * 3 + 0];
            float dy = x[src * 3 + 1] - x[dst * 3 + 1];
            float dz = x[src * 3 + 2] - x[dst * 3 + 2];
            float len = sqrtf(fmaf(dx, dx, fmaf(dy, dy, dz * dz)));
            len = fmaxf(len, 1e-8f);
            float sc = coord_w / len;
            atomicAdd(&out[dst * 3 + 0], sc * dx);
            atomicAdd(&out[dst * 3 + 1], sc * dy);
            atomicAdd(&out[dst * 3 + 2], sc * dz);
        }
    }
}

extern "C" void kernel_launch(void* const* d_in, const int* in_sizes, int n_in,
                              void* d_out, int out_size, void* d_ws, size_t ws_size,
                              hipStream_t stream) {
    const float* x         = (const float*)d_in[0];
    const float* cond      = (const float*)d_in[1];
    const float* edge_dist = (const float*)d_in[2];
    const float* ew1       = (const float*)d_in[3];
    const float* eb1       = (const float*)d_in[4];
    const float* ew2       = (const float*)d_in[5];
    const float* eb2       = (const float*)d_in[6];
    // d_in[7..10] = node_mlp weights: dead code (h_out discarded by reference)
    const float* cw1       = (const float*)d_in[11];
    const float* cb1       = (const float*)d_in[12];
    const float* cw2       = (const float*)d_in[13];
    const int*   edge_index= (const int*)d_in[14];
    const int*   tptr      = (const int*)d_in[15];
    float* out = (float*)d_out;

    const int E  = in_sizes[2];        // 800000
    const int BN = in_sizes[1] / 63;   // 50000
    const int n_out = out_size;        // 150000

    char* ws = (char*)d_ws;
    unsigned short* bt_M = (unsigned short*)(ws);            // 8 KB
    float*          c0   = (float*)(ws + 8192);              // 512 B
    unsigned short* bt2  = (unsigned short*)(ws + 16384);    // 32 KB
    unsigned short* UV   = (unsigned short*)(ws + 65536);    // BN*256*2 = 25.6 MB

    int init_blocks = (n_out + 255) / 256;
    prep_merged_kernel<<<65 + init_blocks, 256, 0, stream>>>(
        x, out, n_out, cw1, bt2, ew2, eb2, cb1, tptr, bt_M, c0);
    prep_uv_kernel<<<(BN + 63) / 64, 256, 0, stream>>>(cond, bt2, UV, BN);

    int blocks = (E + 127) / 128;
    edge_kernel<<<blocks, 256, 0, stream>>>(x, edge_dist, ew1, eb1,
                                            bt_M, c0, cw2, UV,
                                            edge_index, out, E);
}

// Round 9
// 271.536 us; speedup vs baseline: 1.1177x; 1.1177x over previous
//
#include <hip/hip_runtime.h>
#include <hip/hip_bf16.h>

typedef __attribute__((ext_vector_type(8))) short bf16x8;
typedef __attribute__((ext_vector_type(4))) float f32x4;
typedef __attribute__((ext_vector_type(4), aligned(4))) float f32x4u;
typedef __attribute__((ext_vector_type(2), aligned(4))) float f32x2u;

__device__ __forceinline__ unsigned short f2bf(float f) {
    unsigned int u = __float_as_uint(f);
    unsigned int r = (u + 0x7fffu + ((u >> 16) & 1u)) >> 16;
    return (unsigned short)r;
}
__device__ __forceinline__ float bflo(unsigned int u) { return __uint_as_float(u << 16); }
__device__ __forceinline__ float bfhi(unsigned int u) { return __uint_as_float(u & 0xffff0000u); }

__device__ __forceinline__ bf16x8 load8_bf(const float* p) {
    f32x4u a = *(const f32x4u*)p;
    f32x4u b = *(const f32x4u*)(p + 4);
    bf16x8 r;
    r[0] = f2bf(a[0]); r[1] = f2bf(a[1]); r[2] = f2bf(a[2]); r[3] = f2bf(a[3]);
    r[4] = f2bf(b[0]); r[5] = f2bf(b[1]); r[6] = f2bf(b[2]); r[7] = f2bf(b[3]);
    return r;
}
__device__ __forceinline__ bf16x8 load7z_bf(const float* p) {
    f32x4u a = *(const f32x4u*)p;
    f32x2u b = *(const f32x2u*)(p + 4);
    float c = p[6];
    bf16x8 r;
    r[0] = f2bf(a[0]); r[1] = f2bf(a[1]); r[2] = f2bf(a[2]); r[3] = f2bf(a[3]);
    r[4] = f2bf(b[0]); r[5] = f2bf(b[1]); r[6] = f2bf(c);  r[7] = 0;
    return r;
}

// ---- prep: blocks [0,nb_uv) -> UV (bt2 built in LDS); block nb_uv -> consts;
//      blocks (nb_uv, ..] -> out = x ----
// UV layout (r7, the measured-best): byte within node = half*256 + g*32 + kq*8 + r*2,
// i.e. original col c = g*16 + kq*4 + r, halves U(+0)/V(+256).
__global__ __launch_bounds__(256) void prep_kernel(
    const float* __restrict__ x, float* __restrict__ out, int n_out,
    const float* __restrict__ cond, const float* __restrict__ cw1,
    const float* __restrict__ ew2, const float* __restrict__ eb2,
    const float* __restrict__ cb1, const int* __restrict__ tptr,
    unsigned short* __restrict__ bt_M, float* __restrict__ c0,
    unsigned short* __restrict__ UV, int BN, int nb_uv)
{
    const int b = blockIdx.x, tid = threadIdx.x;
    if (b < nb_uv) {
        // bt2[c][k] in LDS, stride 72 shorts (144B: 16B-aligned, bank-spread)
        __shared__ __align__(16) unsigned short bt2[256 * 72];
        {
            const int c = tid;
            const float* colp = (c < 128) ? (cw1 + c) : (cw1 + 64 * 128 + (c - 128));
            for (int k = 0; k < 63; ++k)
                bt2[c * 72 + k] = f2bf(colp[k * 128]);
            bt2[c * 72 + 63] = 0;   // t-channel row folded into c0
        }
        __syncthreads();

        const int lane = tid & 63, wid = tid >> 6;
        const int fr = lane & 15, kq = lane >> 4;
        int node = b * 64 + wid * 16 + fr;
        if (node >= BN) node = BN - 1;
        const float* cp = cond + (long)node * 63;
        bf16x8 b0 = load8_bf(cp + 8 * kq);
        bf16x8 b1 = (kq < 3) ? load8_bf(cp + 32 + 8 * kq) : load7z_bf(cp + 56);

        char* UVb = (char*)UV;
        const unsigned off0 = (unsigned)node * 512u + (unsigned)(kq * 8);
        #pragma unroll
        for (int n = 0; n < 16; ++n) {
            bf16x8 a0 = *reinterpret_cast<const bf16x8*>(&bt2[(n * 16 + fr) * 72 + 8 * kq]);
            bf16x8 a1 = *reinterpret_cast<const bf16x8*>(&bt2[(n * 16 + fr) * 72 + 32 + 8 * kq]);
            f32x4 acc = (f32x4){0.f, 0.f, 0.f, 0.f};
            acc = __builtin_amdgcn_mfma_f32_16x16x32_bf16(a0, b0, acc, 0, 0, 0);
            acc = __builtin_amdgcn_mfma_f32_16x16x32_bf16(a1, b1, acc, 0, 0, 0);
            uint2 pk;
            pk.x = (unsigned)f2bf(acc[0]) | ((unsigned)f2bf(acc[1]) << 16);
            pk.y = (unsigned)f2bf(acc[2]) | ((unsigned)f2bf(acc[3]) << 16);
            *reinterpret_cast<uint2*>(UVb + off0 + n * 32) = pk;
        }
    } else if (b == nb_uv) {
        if (tid < 128) {
            int j = tid;
            float t = (float)tptr[0];
            float cacc = cb1[j] + t * (cw1[63 * 128 + j] + cw1[127 * 128 + j]);
            float m[32];
            #pragma unroll
            for (int p = 0; p < 32; ++p) m[p] = 0.f;
            for (int i = 0; i < 32; ++i) {
                float w = cw1[(128 + i) * 128 + j];
                cacc = fmaf(eb2[i], w, cacc);
                #pragma unroll
                for (int p = 0; p < 32; ++p) m[p] = fmaf(ew2[p * 32 + i], w, m[p]);
            }
            c0[j] = cacc;
            #pragma unroll
            for (int p = 0; p < 32; ++p) bt_M[j * 32 + p] = f2bf(m[p]);
        }
    } else {
        int i = (b - nb_uv - 1) * 256 + tid;
        if (i < n_out) out[i] = x[i];
    }
}

// ---- edge kernel: BARRIER-FREE, each wave owns 32 edges end-to-end ----
__global__ __launch_bounds__(256, 4) void edge_kernel(
    const float* __restrict__ x, const float* __restrict__ edge_dist,
    const float* __restrict__ ew1, const float* __restrict__ eb1,
    const unsigned short* __restrict__ bt_M, const float* __restrict__ c0f,
    const float* __restrict__ cw2, const unsigned short* __restrict__ UV,
    const int* __restrict__ edge_index, float* __restrict__ out, int E)
{
    __shared__ __align__(16) unsigned short s_lds[128][40];  // wave-private 32-row slices
    __shared__ int idx_lds[2][128];
    __shared__ float cw_lds[128];

    const int tid = threadIdx.x, lane = tid & 63, wid = tid >> 6;
    const int fr = lane & 15, kq = lane >> 4;
    const int lp = lane & 31, hf = lane >> 5;
    const int e0w = blockIdx.x * 128 + wid * 32;  // this wave's 32 edges

    // 1) index load + wave-local exchange
    {
        int e = e0w + lp; if (e >= E) e = E - 1;
        idx_lds[hf][wid * 32 + lp] = edge_index[hf ? (E + e) : e];
    }
    asm volatile("s_waitcnt lgkmcnt(0)" ::: "memory");
    int srow[2], drow[2];
    #pragma unroll
    for (int m = 0; m < 2; ++m) {
        srow[m] = idx_lds[0][wid * 32 + m * 16 + fr];
        drow[m] = idx_lds[1][wid * 32 + m * 16 + fr];
    }

    // 2) issue UV gathers EARLY (r7 layout: uint2 per g-group); consumed at acc-init
    const char* UVb = (const char*)UV;
    uint2 Lu[2][8], Lv[2][8];
    #pragma unroll
    for (int m = 0; m < 2; ++m) {
        unsigned bu = (unsigned)srow[m] * 512u + (unsigned)(kq * 8);
        unsigned bv = (unsigned)drow[m] * 512u + 256u + (unsigned)(kq * 8);
        #pragma unroll
        for (int g = 0; g < 8; ++g) {
            Lu[m][g] = *reinterpret_cast<const uint2*>(UVb + bu + g * 32);
            Lv[m][g] = *reinterpret_cast<const uint2*>(UVb + bv + g * 32);
        }
    }

    // 3) silu: lane -> edge (lane>>1), 16 outputs, REGISTER-preloaded weights
    {
        int eh = lane >> 1, j0 = (lane & 1) * 16;
        int e = e0w + eh; if (e >= E) e = E - 1;
        float dist = edge_dist[e];
        f32x4u wv[4], bb[4];
        #pragma unroll
        for (int i = 0; i < 4; ++i) {
            wv[i] = *reinterpret_cast<const f32x4u*>(ew1 + j0 + 4 * i);
            bb[i] = *reinterpret_cast<const f32x4u*>(eb1 + j0 + 4 * i);
        }
        unsigned pk[8];
        #pragma unroll
        for (int i = 0; i < 8; ++i) {
            float a0 = fmaf(dist, wv[i >> 1][(i & 1) * 2 + 0], bb[i >> 1][(i & 1) * 2 + 0]);
            float a1 = fmaf(dist, wv[i >> 1][(i & 1) * 2 + 1], bb[i >> 1][(i & 1) * 2 + 1]);
            float s0 = a0 / (1.f + __expf(-a0));
            float s1 = a1 / (1.f + __expf(-a1));
            pk[i] = (unsigned)f2bf(s0) | ((unsigned)f2bf(s1) << 16);
        }
        uint4 q0 = make_uint4(pk[0], pk[1], pk[2], pk[3]);
        uint4 q1 = make_uint4(pk[4], pk[5], pk[6], pk[7]);
        *reinterpret_cast<uint4*>(&s_lds[wid * 32 + eh][j0]) = q0;
        *reinterpret_cast<uint4*>(&s_lds[wid * 32 + eh][j0 + 8]) = q1;
    }
    asm volatile("s_waitcnt lgkmcnt(0)" ::: "memory");

    // 4) B-frags (edges as MFMA cols): lane(col=fr,kq) holds s[edge][8kq..8kq+7]
    bf16x8 sb[2];
    #pragma unroll
    for (int m = 0; m < 2; ++m)
        sb[m] = *reinterpret_cast<const bf16x8*>(&s_lds[wid * 32 + m * 16 + fr][8 * kq]);

    // 5) two N-halves: acc init = c0 + U + V (frees load regs), MFMA adds s.M, consume
    float psum[2] = {0.f, 0.f};
    #pragma unroll
    for (int nh = 0; nh < 2; ++nh) {
        f32x4 acc[2][4];
        #pragma unroll
        for (int n = 0; n < 4; ++n) {
            const int g = nh * 4 + n;
            f32x4u c = *reinterpret_cast<const f32x4u*>(c0f + g * 16 + kq * 4);
            #pragma unroll
            for (int m = 0; m < 2; ++m) {
                unsigned u0 = Lu[m][g].x, u1 = Lu[m][g].y;
                unsigned v0 = Lv[m][g].x, v1 = Lv[m][g].y;
                acc[m][n] = (f32x4){ c[0] + bflo(u0) + bflo(v0),
                                     c[1] + bfhi(u0) + bfhi(v0),
                                     c[2] + bflo(u1) + bflo(v1),
                                     c[3] + bfhi(u1) + bfhi(v1) };
            }
        }
        #pragma unroll
        for (int n = 0; n < 4; ++n) {
            const int g = nh * 4 + n;
            bf16x8 aw = *reinterpret_cast<const bf16x8*>(&bt_M[(g * 16 + fr) * 32 + 8 * kq]);
            acc[0][n] = __builtin_amdgcn_mfma_f32_16x16x32_bf16(aw, sb[0], acc[0][n], 0, 0, 0);
            acc[1][n] = __builtin_amdgcn_mfma_f32_16x16x32_bf16(aw, sb[1], acc[1][n], 0, 0, 0);
        }
        #pragma unroll
        for (int n = 0; n < 4; ++n) {
            const int g = nh * 4 + n;
            f32x4u w2 = *reinterpret_cast<const f32x4u*>(cw2 + g * 16 + kq * 4);
            #pragma unroll
            for (int m = 0; m < 2; ++m)
                #pragma unroll
                for (int r = 0; r < 4; ++r) {
                    float h = acc[m][n][r];
                    float sil = h / (1.f + __expf(-h));
                    psum[m] = fmaf(sil, w2[r], psum[m]);
                }
        }
    }

    // 6) kq-reduce, wave-local exchange, epilogue
    #pragma unroll
    for (int m = 0; m < 2; ++m) {
        psum[m] += __shfl_xor(psum[m], 16, 64);
        psum[m] += __shfl_xor(psum[m], 32, 64);
    }
    if (kq == 0) {
        #pragma unroll
        for (int m = 0; m < 2; ++m)
            cw_lds[wid * 32 + m * 16 + fr] = psum[m];
    }
    asm volatile("s_waitcnt lgkmcnt(0)" ::: "memory");
    if (lane < 32) {
        int e = e0w + lp;
        if (e < E) {
            float coord_w = cw_lds[wid * 32 + lp];
            int src = idx_lds[0][wid * 32 + lp];
            int dst = idx_lds[1][wid * 32 + lp];
            float dx = x[src * 3 + 0] - x[dst * 3 + 0];
            float dy = x[src * 3 + 1] - x[dst * 3 + 1];
            float dz = x[src * 3 + 2] - x[dst * 3 + 2];
            float len = sqrtf(fmaf(dx, dx, fmaf(dy, dy, dz * dz)));
            len = fmaxf(len, 1e-8f);
            float sc = coord_w / len;
            atomicAdd(&out[dst * 3 + 0], sc * dx);
            atomicAdd(&out[dst * 3 + 1], sc * dy);
            atomicAdd(&out[dst * 3 + 2], sc * dz);
        }
    }
}

extern "C" void kernel_launch(void* const* d_in, const int* in_sizes, int n_in,
                              void* d_out, int out_size, void* d_ws, size_t ws_size,
                              hipStream_t stream) {
    const float* x         = (const float*)d_in[0];
    const float* cond      = (const float*)d_in[1];
    const float* edge_dist = (const float*)d_in[2];
    const float* ew1       = (const float*)d_in[3];
    const float* eb1       = (const float*)d_in[4];
    const float* ew2       = (const float*)d_in[5];
    const float* eb2       = (const float*)d_in[6];
    // d_in[7..10] = node_mlp weights: dead code (h_out discarded by reference)
    const float* cw1       = (const float*)d_in[11];
    const float* cb1       = (const float*)d_in[12];
    const float* cw2       = (const float*)d_in[13];
    const int*   edge_index= (const int*)d_in[14];
    const int*   tptr      = (const int*)d_in[15];
    float* out = (float*)d_out;

    const int E  = in_sizes[2];        // 800000
    const int BN = in_sizes[1] / 63;   // 50000
    const int n_out = out_size;        // 150000

    char* ws = (char*)d_ws;
    unsigned short* bt_M = (unsigned short*)(ws);            // 8 KB
    float*          c0   = (float*)(ws + 8192);              // 512 B
    unsigned short* UV   = (unsigned short*)(ws + 65536);    // BN*256*2 = 25.6 MB

    const int nb_uv = (BN + 63) / 64;
    const int nb_out = (n_out + 255) / 256;
    prep_kernel<<<nb_uv + 1 + nb_out, 256, 0, stream>>>(
        x, out, n_out, cond, cw1, ew2, eb2, cb1, tptr, bt_M, c0, UV, BN, nb_uv);

    int blocks = (E + 127) / 128;
    edge_kernel<<<blocks, 256, 0, stream>>>(x, edge_dist, ew1, eb1,
                                            bt_M, c0, cw2, UV,
                                            edge_index, out, E);
}